// Round 8
// baseline (893.145 us; speedup 1.0000x reference)
//
#include <hip/hip_runtime.h>
#include <cstddef>
#include <cstring>

#define HW 16384
#define CC 128
#define NB 8
#define GB 4   // batches per group

typedef short bf16x8_t __attribute__((ext_vector_type(8)));
typedef float floatx4 __attribute__((ext_vector_type(4)));

__device__ inline unsigned short f2bf(float f) {
  unsigned u; __builtin_memcpy(&u, &f, 4);
  u += 0x7fffu + ((u >> 16) & 1u);
  return (unsigned short)(u >> 16);
}
__device__ inline float bf2f(unsigned short s) {
  unsigned u = ((unsigned)s) << 16; float f; __builtin_memcpy(&f, &u, 4);
  return f;
}

// ---------------- LayerNorm stats (mean / rstd per (b,p)), all 8 batches ----
__global__ __launch_bounds__(256) void k_ln_stats(const float* __restrict__ x,
                                                  float* __restrict__ mean,
                                                  float* __restrict__ rstd) {
  int idx = blockIdx.x * 256 + threadIdx.x;   // 0 .. 131071
  int b = idx >> 14;
  int p = idx & (HW - 1);
  const float* xp = x + ((size_t)b << 21) + p;
  float s = 0.f, ss = 0.f;
  for (int c = 0; c < CC; ++c) {
    float v = xp[(size_t)c << 14];
    s += v;
    ss += v * v;
  }
  float m = s * (1.0f / CC);
  float var = ss * (1.0f / CC) - m * m;
  mean[idx] = m;
  rstd[idx] = rsqrtf(var + 1e-5f);
}

// ---------------- precompute hi/lo bf16 planes for conv weights (g folded)
// and bf16 plane for lw. whl: 6 sets x [hi 16384][lo 16384]. lwh: 32768.
__global__ __launch_bounds__(256) void k_wsplit(
    const float* __restrict__ qw1, const float* __restrict__ kw2,
    const float* __restrict__ vw2, const float* __restrict__ qw2,
    const float* __restrict__ kw1, const float* __restrict__ vw1,
    const float* __restrict__ g1, const float* __restrict__ g2,
    const float* __restrict__ lw, unsigned short* __restrict__ whl,
    unsigned short* __restrict__ lwh) {
  int idx = blockIdx.x * 256 + threadIdx.x;   // 0 .. 131071
  if (idx < 98304) {
    const int set = idx >> 14;
    const int e = idx & 16383;
    const int c = e & 127;
    const float* W; const float* g;
    switch (set) {
      case 0: W = qw1; g = g1; break;
      case 1: W = kw2; g = g2; break;
      case 2: W = vw2; g = g2; break;
      case 3: W = qw2; g = g2; break;
      case 4: W = kw1; g = g1; break;
      default: W = vw1; g = g1; break;
    }
    float v = W[e] * g[c];
    unsigned short h = f2bf(v);
    whl[set * 32768 + e] = h;
    whl[set * 32768 + 16384 + e] = f2bf(v - bf2f(h));
  } else {
    int e2 = idx - 98304;           // 0 .. 32767
    lwh[e2] = f2bf(lw[e2]);
  }
}

// ---------------- split-bf16 MFMA LN+1x1 conv (A-side direct from global) ---
// Y[o,p] = sum_c (W[o,c]*g[c]) * (X[c,p]-mu_p)*r_p + bias[o]
// 3 MFMA passes hi*hi + hi*lo + lo*hi => ~fp32 accuracy.
__global__ __launch_bounds__(256) void k_conv1x1_mfma(
    const float* __restrict__ X, const unsigned short* __restrict__ Wh,
    const float* __restrict__ bias,
    const float* __restrict__ mean, const float* __restrict__ rstd,
    float* __restrict__ Y, int b0) {
  __shared__ __align__(16) float raw[32][132];   // X chunk [c][p]
  __shared__ __align__(16) short Bh[128][40];    // Xn hi [p][c_local]
  __shared__ __align__(16) short Bl[128][40];
  const unsigned short* Wl = Wh + 16384;
  const int bl = blockIdx.y;
  const int b = b0 + bl;
  const int p0 = blockIdx.x * 128;
  const int t = threadIdx.x;
  const int lane = t & 63, wv = t >> 6;
  const int quad = lane >> 4, l15 = lane & 15;
  const int wr = wv >> 1, wc = wv & 1;

  const int s1c = t >> 3, s1p = (t & 7) * 16;
  const int s2p = t & 127, s2o = t >> 7;
  const float mu = mean[b * HW + p0 + s2p];
  const float rs = rstd[b * HW + p0 + s2p];

  const float* Xb = X + ((size_t)b << 21);
  floatx4 acc[4][4];
#pragma unroll
  for (int i = 0; i < 4; ++i)
#pragma unroll
    for (int j = 0; j < 4; ++j) acc[i][j] = (floatx4){0.f, 0.f, 0.f, 0.f};

  for (int k0 = 0; k0 < 128; k0 += 32) {
    // stage 1: X[c][p] chunk -> raw (coalesced)
    {
      const float* xp = Xb + ((size_t)(k0 + s1c) << 14) + p0 + s1p;
#pragma unroll
      for (int u = 0; u < 4; ++u)
        *reinterpret_cast<float4*>(&raw[s1c][s1p + 4 * u]) =
            *reinterpret_cast<const float4*>(xp + 4 * u);
    }
    __syncthreads();
    // stage 2: transpose + LN + hi/lo split
#pragma unroll
    for (int item = 0; item < 2; ++item) {
      const int oct = s2o + 2 * item;     // 0..3
      short th[8], tl[8];
#pragma unroll
      for (int jj = 0; jj < 8; ++jj) {
        float v = (raw[oct * 8 + jj][s2p] - mu) * rs;
        unsigned short h = f2bf(v);
        th[jj] = (short)h;
        tl[jj] = (short)f2bf(v - bf2f(h));
      }
      *reinterpret_cast<bf16x8_t*>(&Bh[s2p][oct * 8]) =
          *reinterpret_cast<bf16x8_t*>(&th[0]);
      *reinterpret_cast<bf16x8_t*>(&Bl[s2p][oct * 8]) =
          *reinterpret_cast<bf16x8_t*>(&tl[0]);
    }
    __syncthreads();
    // A fragments straight from precomputed global planes (L2-hot)
    bf16x8_t afh[4], afl[4], bfh[4], bfl[4];
#pragma unroll
    for (int i = 0; i < 4; ++i) {
      const int m = wr * 64 + i * 16 + l15;
      const unsigned short* wp = Wh + m * 128 + k0 + quad * 8;
      afh[i] = *reinterpret_cast<const bf16x8_t*>(wp);
      afl[i] = *reinterpret_cast<const bf16x8_t*>(Wl + m * 128 + k0 + quad * 8);
    }
#pragma unroll
    for (int j = 0; j < 4; ++j) {
      const int p = wc * 64 + j * 16 + l15;
      bfh[j] = *reinterpret_cast<const bf16x8_t*>(&Bh[p][quad * 8]);
      bfl[j] = *reinterpret_cast<const bf16x8_t*>(&Bl[p][quad * 8]);
    }
#pragma unroll
    for (int i = 0; i < 4; ++i)
#pragma unroll
      for (int j = 0; j < 4; ++j) {
        acc[i][j] = __builtin_amdgcn_mfma_f32_16x16x32_bf16(afh[i], bfh[j], acc[i][j], 0, 0, 0);
        acc[i][j] = __builtin_amdgcn_mfma_f32_16x16x32_bf16(afh[i], bfl[j], acc[i][j], 0, 0, 0);
        acc[i][j] = __builtin_amdgcn_mfma_f32_16x16x32_bf16(afl[i], bfh[j], acc[i][j], 0, 0, 0);
      }
    __syncthreads();   // protect raw/Bh/Bl for next k0
  }
  float* Yb = Y + ((size_t)bl << 21);
#pragma unroll
  for (int i = 0; i < 4; ++i) {
#pragma unroll
    for (int j = 0; j < 4; ++j) {
#pragma unroll
      for (int r = 0; r < 4; ++r) {
        const int o = wr * 64 + i * 16 + quad * 4 + r;
        const int p = p0 + wc * 64 + j * 16 + l15;
        Yb[((size_t)o << 14) + p] = acc[i][j][r] + bias[o];
      }
    }
  }
}

// ---------------- split-bf16 MFMA score GEMM with fused depthwise 3x3 --------
// sub-chunked raw (16 rows) -> 49.4 KB LDS -> 3 blocks/CU.
__global__ __launch_bounds__(256) void k_score_mfma(
    const float* __restrict__ Yq, const float* __restrict__ Yk,
    const float* __restrict__ qdw, const float* __restrict__ qdb,
    const float* __restrict__ kdw, const float* __restrict__ kdb,
    float* __restrict__ P) {
  __shared__ __align__(16) float raw[16][132];   // dw out sub-chunk [h][w]
  __shared__ __align__(16) short Ah[128][40];    // Q side [w][h] hi
  __shared__ __align__(16) short Al[128][40];
  __shared__ __align__(16) short Bh[128][40];    // K side [w][h] hi
  __shared__ __align__(16) short Bl[128][40];
  const int ch = blockIdx.x;
  const int bl = blockIdx.y;
  const int t = threadIdx.x;
  const int lane = t & 63, wv = t >> 6;
  const int quad = lane >> 4, l15 = lane & 15;
  const int wr = wv >> 1, wc = wv & 1;
  const int hl = t >> 4;           // 0..15 row within sub-chunk
  const int w0 = (t & 15) * 8;     // 0..120, 8 widths per thread
  const int s2w = t & 127, s2o = t >> 7;
  const int cc = ch;
  const float* Yqb = Yq + ((size_t)bl << 21) + ((size_t)cc << 14);
  const float* Ykb = Yk + ((size_t)bl << 21) + ((size_t)cc << 14);
  const float* qwt = qdw + cc * 9;
  const float* kwt = kdw + cc * 9;
  const float qbv = qdb[cc], kbv = kdb[cc];

  floatx4 acc[4][4];
#pragma unroll
  for (int i = 0; i < 4; ++i)
#pragma unroll
    for (int j = 0; j < 4; ++j) acc[i][j] = (floatx4){0.f, 0.f, 0.f, 0.f};

  for (int k0 = 0; k0 < 128; k0 += 32) {
#pragma unroll
    for (int side = 0; side < 2; ++side) {
      const float* Yc = side ? Ykb : Yqb;
      const float* wt = side ? kwt : qwt;
      const float bias = side ? kbv : qbv;
      short* dh = side ? &Bh[0][0] : &Ah[0][0];
      short* dl = side ? &Bl[0][0] : &Al[0][0];
#pragma unroll
      for (int sub = 0; sub < 2; ++sub) {
        // ---- fused dw 3x3 for 8 outputs at view-row h ----
        const int h = k0 + sub * 16 + hl;
        float a[8];
#pragma unroll
        for (int j = 0; j < 8; ++j) a[j] = bias;
#pragma unroll
        for (int dy = 0; dy < 3; ++dy) {
          const int hh = h + dy - 1;
          if (hh < 0 || hh > 127) continue;
          const float* rp = Yc + (hh << 7) + w0;
          float4 f0 = *reinterpret_cast<const float4*>(rp);
          float4 f1 = *reinterpret_cast<const float4*>(rp + 4);
          float v[10];
          v[0] = (w0 > 0) ? rp[-1] : 0.f;
          v[1] = f0.x; v[2] = f0.y; v[3] = f0.z; v[4] = f0.w;
          v[5] = f1.x; v[6] = f1.y; v[7] = f1.z; v[8] = f1.w;
          v[9] = (w0 < 120) ? rp[8] : 0.f;
          const float wa = wt[dy * 3 + 0], wb = wt[dy * 3 + 1], wc2 = wt[dy * 3 + 2];
#pragma unroll
          for (int j = 0; j < 8; ++j)
            a[j] = fmaf(v[j], wa, fmaf(v[j + 1], wb, fmaf(v[j + 2], wc2, a[j])));
        }
        *reinterpret_cast<float4*>(&raw[hl][w0]) = (float4){a[0], a[1], a[2], a[3]};
        *reinterpret_cast<float4*>(&raw[hl][w0 + 4]) = (float4){a[4], a[5], a[6], a[7]};
        __syncthreads();
        // ---- transpose [h][w] -> [w][h] + hi/lo split ----
        short th[8], tl[8];
#pragma unroll
        for (int jj = 0; jj < 8; ++jj) {
          float v = raw[s2o * 8 + jj][s2w];
          unsigned short hb = f2bf(v);
          th[jj] = (short)hb;
          tl[jj] = (short)f2bf(v - bf2f(hb));
        }
        *reinterpret_cast<bf16x8_t*>(&dh[s2w * 40 + sub * 16 + s2o * 8]) =
            *reinterpret_cast<bf16x8_t*>(&th[0]);
        *reinterpret_cast<bf16x8_t*>(&dl[s2w * 40 + sub * 16 + s2o * 8]) =
            *reinterpret_cast<bf16x8_t*>(&tl[0]);
        __syncthreads();
      }
    }
    // ---- MFMA, 3 split passes ----
    bf16x8_t afh[4], afl[4], bfh[4], bfl[4];
#pragma unroll
    for (int i = 0; i < 4; ++i) {
      const int m = wr * 64 + i * 16 + l15;
      afh[i] = *reinterpret_cast<const bf16x8_t*>(&Ah[m][quad * 8]);
      afl[i] = *reinterpret_cast<const bf16x8_t*>(&Al[m][quad * 8]);
    }
#pragma unroll
    for (int j = 0; j < 4; ++j) {
      const int n = wc * 64 + j * 16 + l15;
      bfh[j] = *reinterpret_cast<const bf16x8_t*>(&Bh[n][quad * 8]);
      bfl[j] = *reinterpret_cast<const bf16x8_t*>(&Bl[n][quad * 8]);
    }
#pragma unroll
    for (int i = 0; i < 4; ++i)
#pragma unroll
      for (int j = 0; j < 4; ++j) {
        acc[i][j] = __builtin_amdgcn_mfma_f32_16x16x32_bf16(afh[i], bfh[j], acc[i][j], 0, 0, 0);
        acc[i][j] = __builtin_amdgcn_mfma_f32_16x16x32_bf16(afh[i], bfl[j], acc[i][j], 0, 0, 0);
        acc[i][j] = __builtin_amdgcn_mfma_f32_16x16x32_bf16(afl[i], bfh[j], acc[i][j], 0, 0, 0);
      }
  }
  float* Pp = P + ((size_t)(ch * GB + bl) << 14);
#pragma unroll
  for (int i = 0; i < 4; ++i) {
#pragma unroll
    for (int j = 0; j < 4; ++j) {
#pragma unroll
      for (int r = 0; r < 4; ++r) {
        const int c = wr * 64 + i * 16 + quad * 4 + r;
        const int d = wc * 64 + j * 16 + l15;
        Pp[c * 128 + d] = acc[i][j][r];
      }
    }
  }
}

// ---------------- reduce split-K partials -> S (GB batches) ----------------
__global__ __launch_bounds__(256) void k_score_reduce(const float* __restrict__ P,
                                                      float* __restrict__ S) {
  int idx = blockIdx.x * 256 + threadIdx.x;
  int bl = idx >> 14;
  int rem = idx & 16383;
  float s = 0.f;
  for (int c = 0; c < 128; ++c) s += P[((size_t)(c * GB + bl) << 14) + rem];
  S[idx] = s;
}

// ---------------- softmax over rows of 128 ----------------
__global__ __launch_bounds__(128) void k_softmax(float* __restrict__ S) {
  __shared__ float red[128];
  const int row = blockIdx.x;
  const int t = threadIdx.x;
  float v = S[row * 128 + t];
  red[t] = v;
  __syncthreads();
  for (int s = 64; s > 0; s >>= 1) {
    if (t < s) red[t] = fmaxf(red[t], red[t + s]);
    __syncthreads();
  }
  float mx = red[0];
  __syncthreads();
  float e = expf(v - mx);
  red[t] = e;
  __syncthreads();
  for (int s = 64; s > 0; s >>= 1) {
    if (t < s) red[t] += red[t + s];
    __syncthreads();
  }
  S[row * 128 + t] = e / red[0];
}

// ---------------- depthwise 3x3 + transpose: Vt[p][c] bf16 -----------------
__global__ __launch_bounds__(256) void k_dw_t(const float* __restrict__ Y,
                                              const float* __restrict__ Kw,
                                              const float* __restrict__ db,
                                              unsigned short* __restrict__ Vt) {
  __shared__ unsigned short T[128][33];
  const int h = blockIdx.x;
  const int c0 = blockIdx.y * 32;
  const int bl = blockIdx.z;
  const int t = threadIdx.x;
  const int cl = t >> 3;
  const int w0 = (t & 7) * 16;
  const int c = c0 + cl;
  const float* Yc = Y + ((size_t)bl << 21) + ((size_t)c << 14);
  const float* wt = Kw + c * 9;
  float a[16];
#pragma unroll
  for (int j = 0; j < 16; ++j) a[j] = db[c];
#pragma unroll
  for (int dy = 0; dy < 3; ++dy) {
    const int hh = h + dy - 1;
    if (hh < 0 || hh > 127) continue;
    const float* rp = Yc + (hh << 7) + w0;
    float4 f0 = *reinterpret_cast<const float4*>(rp);
    float4 f1 = *reinterpret_cast<const float4*>(rp + 4);
    float4 f2 = *reinterpret_cast<const float4*>(rp + 8);
    float4 f3 = *reinterpret_cast<const float4*>(rp + 12);
    float s[18];
    s[1] = f0.x;  s[2] = f0.y;  s[3] = f0.z;  s[4] = f0.w;
    s[5] = f1.x;  s[6] = f1.y;  s[7] = f1.z;  s[8] = f1.w;
    s[9] = f2.x;  s[10] = f2.y; s[11] = f2.z; s[12] = f2.w;
    s[13] = f3.x; s[14] = f3.y; s[15] = f3.z; s[16] = f3.w;
    s[0] = (w0 > 0) ? rp[-1] : 0.f;
    s[17] = (w0 < 112) ? rp[16] : 0.f;
    const float wa = wt[dy * 3 + 0], wb = wt[dy * 3 + 1], wc2 = wt[dy * 3 + 2];
#pragma unroll
    for (int j = 0; j < 16; ++j)
      a[j] = fmaf(s[j], wa, fmaf(s[j + 1], wb, fmaf(s[j + 2], wc2, a[j])));
  }
#pragma unroll
  for (int j = 0; j < 16; ++j) T[w0 + j][cl] = f2bf(a[j]);
  __syncthreads();
  const int w = t >> 1, half = t & 1;
  unsigned short tmp[16];
#pragma unroll
  for (int j = 0; j < 16; ++j) tmp[j] = T[w][half * 16 + j];
  uint4 v0, v1;
  unsigned* vp0 = reinterpret_cast<unsigned*>(&v0);
  unsigned* vp1 = reinterpret_cast<unsigned*>(&v1);
#pragma unroll
  for (int j = 0; j < 4; ++j) {
    vp0[j] = (unsigned)tmp[2 * j] | ((unsigned)tmp[2 * j + 1] << 16);
    vp1[j] = (unsigned)tmp[8 + 2 * j] | ((unsigned)tmp[8 + 2 * j + 1] << 16);
  }
  unsigned short* dst = Vt + ((size_t)bl << 21) + ((size_t)((h << 7) + w) << 7)
                        + c0 + half * 16;
  *reinterpret_cast<uint4*>(dst) = v0;
  *reinterpret_cast<uint4*>(dst + 8) = v1;
}

// ---------------- MFMA: O[c,p] = sum_d Att[c,d] * V[d,p] -------------------
// no LDS: S rows are k-contiguous, converted to bf16 in registers.
// N-split: 64-pixel tiles, grid (256, GB).
__global__ __launch_bounds__(256) void k_av_mfma(
    const float* __restrict__ S, const unsigned short* __restrict__ Vt,
    unsigned short* __restrict__ O) {
  const int bl = blockIdx.y;
  const int p0 = blockIdx.x * 64;
  const int t = threadIdx.x;
  const int lane = t & 63, wv = t >> 6;
  const int quad = lane >> 4, l15 = lane & 15;
  const int wr = wv >> 1, wc = wv & 1;
  const float* Sb = S + ((size_t)bl << 14);
  floatx4 acc[4][2];
#pragma unroll
  for (int i = 0; i < 4; ++i)
#pragma unroll
    for (int j = 0; j < 2; ++j) acc[i][j] = (floatx4){0.f, 0.f, 0.f, 0.f};
  const unsigned short* Vb = Vt + ((size_t)bl << 21);
#pragma unroll
  for (int d0 = 0; d0 < 128; d0 += 32) {
    bf16x8_t af[4], bf[2];
#pragma unroll
    for (int i = 0; i < 4; ++i) {
      const int m = wr * 64 + i * 16 + l15;
      const float* sp = Sb + m * 128 + d0 + quad * 8;
      float4 x0 = *reinterpret_cast<const float4*>(sp);
      float4 x1 = *reinterpret_cast<const float4*>(sp + 4);
      short tmp[8];
      tmp[0] = (short)f2bf(x0.x); tmp[1] = (short)f2bf(x0.y);
      tmp[2] = (short)f2bf(x0.z); tmp[3] = (short)f2bf(x0.w);
      tmp[4] = (short)f2bf(x1.x); tmp[5] = (short)f2bf(x1.y);
      tmp[6] = (short)f2bf(x1.z); tmp[7] = (short)f2bf(x1.w);
      af[i] = *reinterpret_cast<bf16x8_t*>(&tmp[0]);
    }
#pragma unroll
    for (int j = 0; j < 2; ++j) {
      const int p = p0 + wc * 32 + j * 16 + l15;
      bf[j] = *reinterpret_cast<const bf16x8_t*>(Vb + ((size_t)p << 7) + d0 + quad * 8);
    }
#pragma unroll
    for (int i = 0; i < 4; ++i)
#pragma unroll
      for (int j = 0; j < 2; ++j)
        acc[i][j] = __builtin_amdgcn_mfma_f32_16x16x32_bf16(af[i], bf[j], acc[i][j], 0, 0, 0);
  }
  unsigned short* Ob = O + ((size_t)bl << 21);
#pragma unroll
  for (int i = 0; i < 4; ++i) {
#pragma unroll
    for (int j = 0; j < 2; ++j) {
#pragma unroll
      for (int r = 0; r < 4; ++r) {
        const int c = wr * 64 + i * 16 + quad * 4 + r;
        const int p = p0 + wc * 32 + j * 16 + l15;
        Ob[((size_t)c << 14) + p] = f2bf(acc[i][j][r]);
      }
    }
  }
}

// ---------------- MFMA final: both lw-halves fused, no LDS, N-split --------
// out[b,c2,h2,w2] = sum_k A1[bl,n=w2,c2*128+k]*lw[h2,k]
//                 + sum_k A2[bl,n=w2,c2*128+k]*lw[h2,128+k] + lb + Fi + Fw
__global__ __launch_bounds__(256) void k_final2_mfma(
    const unsigned short* __restrict__ A1, const unsigned short* __restrict__ A2,
    const unsigned short* __restrict__ lwh, const float* __restrict__ lb,
    const float* __restrict__ Fi, const float* __restrict__ Fw,
    float* __restrict__ out, int b0) {
  const int c2 = blockIdx.x;
  const int bl = blockIdx.y;
  const int nb = blockIdx.z * 64;
  const int b = b0 + bl;
  const int t = threadIdx.x;
  const int lane = t & 63, wv = t >> 6;
  const int quad = lane >> 4, l15 = lane & 15;
  const int wr = wv >> 1, wc = wv & 1;
  floatx4 acc[4][2];
#pragma unroll
  for (int i = 0; i < 4; ++i)
#pragma unroll
    for (int j = 0; j < 2; ++j) acc[i][j] = (floatx4){0.f, 0.f, 0.f, 0.f};
#pragma unroll
  for (int phase = 0; phase < 2; ++phase) {
    const unsigned short* Ub = (phase ? A2 : A1) + ((size_t)bl << 21) + c2 * 128;
#pragma unroll
    for (int d0 = 0; d0 < 128; d0 += 32) {
      bf16x8_t af[4], bf[2];
#pragma unroll
      for (int i = 0; i < 4; ++i) {
        const int m = wr * 64 + i * 16 + l15;
        af[i] = *reinterpret_cast<const bf16x8_t*>(
            lwh + m * 256 + phase * 128 + d0 + quad * 8);
      }
#pragma unroll
      for (int j = 0; j < 2; ++j) {
        const int n = nb + wc * 32 + j * 16 + l15;
        bf[j] = *reinterpret_cast<const bf16x8_t*>(Ub + ((size_t)n << 14) + d0 + quad * 8);
      }
#pragma unroll
      for (int i = 0; i < 4; ++i)
#pragma unroll
        for (int j = 0; j < 2; ++j)
          acc[i][j] = __builtin_amdgcn_mfma_f32_16x16x32_bf16(af[i], bf[j], acc[i][j], 0, 0, 0);
    }
  }
  const size_t obase = ((size_t)b << 21) + ((size_t)c2 << 14);
#pragma unroll
  for (int i = 0; i < 4; ++i) {
#pragma unroll
    for (int j = 0; j < 2; ++j) {
#pragma unroll
      for (int r = 0; r < 4; ++r) {
        const int h2 = wr * 64 + i * 16 + quad * 4 + r;
        const int w2 = nb + wc * 32 + j * 16 + l15;
        const size_t a = obase + ((size_t)h2 << 7) + w2;
        out[a] = acc[i][j][r] + lb[h2] + Fi[a] + Fw[a];
      }
    }
  }
}

extern "C" void kernel_launch(void* const* d_in, const int* in_sizes, int n_in,
                              void* d_out, int out_size, void* d_ws, size_t ws_size,
                              hipStream_t stream) {
  const float* F_i  = (const float*)d_in[0];
  const float* F_w  = (const float*)d_in[1];
  const float* g1   = (const float*)d_in[2];
  const float* g2   = (const float*)d_in[3];
  const float* qw1  = (const float*)d_in[4];
  const float* kw1  = (const float*)d_in[5];
  const float* vw1  = (const float*)d_in[6];
  const float* qw2  = (const float*)d_in[7];
  const float* kw2  = (const float*)d_in[8];
  const float* vw2  = (const float*)d_in[9];
  const float* qb1  = (const float*)d_in[10];
  const float* kb1  = (const float*)d_in[11];
  const float* vb1  = (const float*)d_in[12];
  const float* qb2  = (const float*)d_in[13];
  const float* kb2  = (const float*)d_in[14];
  const float* vb2  = (const float*)d_in[15];
  const float* qdw1 = (const float*)d_in[16];
  const float* kdw1 = (const float*)d_in[17];
  const float* vdw1 = (const float*)d_in[18];
  const float* qdw2 = (const float*)d_in[19];
  const float* kdw2 = (const float*)d_in[20];
  const float* vdw2 = (const float*)d_in[21];
  const float* qdb1 = (const float*)d_in[22];
  const float* kdb1 = (const float*)d_in[23];
  const float* vdb1 = (const float*)d_in[24];
  const float* qdb2 = (const float*)d_in[25];
  const float* kdb2 = (const float*)d_in[26];
  const float* vdb2 = (const float*)d_in[27];
  const float* lw   = (const float*)d_in[28];
  const float* lb   = (const float*)d_in[29];
  float* out = (float*)d_out;

  // ---- workspace (~114.7 MiB peak; <=116 MiB proven safe) ----
  char* w = (char*)d_ws;
  const size_t NTOT = (size_t)NB * HW;                      // 131072
  float* meanI = (float*)w; w += NTOT * 4;
  float* rstdI = (float*)w; w += NTOT * 4;
  float* meanW = (float*)w; w += NTOT * 4;
  float* rstdW = (float*)w; w += NTOT * 4;
  float* S     = (float*)w; w += (size_t)GB * HW * 4;       // 0.25 MiB
  unsigned short* whl = (unsigned short*)w; w += 6 * 32768 * 2;  // 384 KiB
  unsigned short* lwh = (unsigned short*)w; w += 32768 * 2;      // 64 KiB
  float* P     = (float*)w; w += (size_t)128 * GB * HW * 4; // 32 MiB
  float* Yq    = (float*)w; w += ((size_t)GB << 21) * 4;    // 32 MiB
  char*  Ykreg = w;         w += ((size_t)GB << 21) * 4;    // 32 MiB (overlaid)
  float* Yk    = (float*)Ykreg;
  unsigned short* Vt = (unsigned short*)Ykreg;                            // 16 MiB
  unsigned short* A2 = (unsigned short*)(Ykreg + ((size_t)GB << 21) * 2); // 16 MiB
  unsigned short* A1 = (unsigned short*)w; w += ((size_t)GB << 21) * 2;   // 16 MiB

  dim3 blk(256);
  k_ln_stats<<<dim3(512), blk, 0, stream>>>(F_i, meanI, rstdI);
  k_ln_stats<<<dim3(512), blk, 0, stream>>>(F_w, meanW, rstdW);
  k_wsplit<<<dim3(512), blk, 0, stream>>>(qw1, kw2, vw2, qw2, kw1, vw1,
                                          g1, g2, lw, whl, lwh);
  const unsigned short* wQ1 = whl;
  const unsigned short* wK2 = whl + 32768;
  const unsigned short* wV2 = whl + 65536;
  const unsigned short* wQ2 = whl + 98304;
  const unsigned short* wK1 = whl + 131072;
  const unsigned short* wV1 = whl + 163840;

  for (int b0 = 0; b0 < NB; b0 += GB) {
    // ---- attention 1: a1 = softmax(Qi^T Kw) ; Aw = a1 @ Vw -> A1 ----
    k_conv1x1_mfma<<<dim3(128, GB), blk, 0, stream>>>(F_i, wQ1, qb1, meanI, rstdI, Yq, b0);
    k_conv1x1_mfma<<<dim3(128, GB), blk, 0, stream>>>(F_w, wK2, kb2, meanW, rstdW, Yk, b0);
    k_score_mfma<<<dim3(128, GB), blk, 0, stream>>>(Yq, Yk, qdw1, qdb1, kdw2, kdb2, P);
    k_score_reduce<<<dim3(GB * HW / 256), blk, 0, stream>>>(P, S);
    k_softmax<<<dim3(GB * 128), dim3(128), 0, stream>>>(S);
    k_conv1x1_mfma<<<dim3(128, GB), blk, 0, stream>>>(F_w, wV2, vb2, meanW, rstdW, Yq, b0);
    k_dw_t<<<dim3(128, 4, GB), blk, 0, stream>>>(Yq, vdw2, vdb2, Vt);
    k_av_mfma<<<dim3(256, GB), blk, 0, stream>>>(S, Vt, A1);

    // ---- attention 2: a2 = softmax(Qw^T Ki) ; Ai = a2 @ Vi -> A2 ----
    k_conv1x1_mfma<<<dim3(128, GB), blk, 0, stream>>>(F_w, wQ2, qb2, meanW, rstdW, Yq, b0);
    k_conv1x1_mfma<<<dim3(128, GB), blk, 0, stream>>>(F_i, wK1, kb1, meanI, rstdI, Yk, b0);
    k_score_mfma<<<dim3(128, GB), blk, 0, stream>>>(Yq, Yk, qdw2, qdb2, kdw1, kdb1, P);
    k_score_reduce<<<dim3(GB * HW / 256), blk, 0, stream>>>(P, S);
    k_softmax<<<dim3(GB * 128), dim3(128), 0, stream>>>(S);
    k_conv1x1_mfma<<<dim3(128, GB), blk, 0, stream>>>(F_i, wV1, vb1, meanI, rstdI, Yq, b0);
    k_dw_t<<<dim3(128, 4, GB), blk, 0, stream>>>(Yq, vdw1, vdb1, Vt);
    k_av_mfma<<<dim3(256, GB), blk, 0, stream>>>(S, Vt, A2);

    // ---- fused final linear + residual (single out write) ----
    k_final2_mfma<<<dim3(128, GB, 2), blk, 0, stream>>>(A1, A2, lwh, lb, F_i, F_w, out, b0);
  }
}